// Round 7
// baseline (400.238 us; speedup 1.0000x reference)
//
#include <hip/hip_runtime.h>
#include <hip/hip_bf16.h>
#include <stdint.h>

#define NN 50000
#define EE 800000
#define DD 128
#define LL 3
// CSR fill (R1-proven config): 196 chunks, x8 XCD ranges -> 1568 blocks, 4-wide ILP.
#define FILL_CHUNKS 196

// front_kernel block partition
#define DEG_BLOCKS 782                      // ceil(EE/4/256)
#define CONV_BLOCKS 6250                    // NN*128/4/256 exact
#define REPACK_BLOCKS 48                    // LL*8*8*64/256 exact

typedef __attribute__((ext_vector_type(8))) short short8;
typedef __attribute__((ext_vector_type(4))) float float4v;

__device__ __forceinline__ float bf2f(unsigned int u) {
  union { unsigned int i; float f; } x; x.i = u << 16; return x.f;
}
__device__ __forceinline__ unsigned short f2bf(float f) {
  union { float f; unsigned int i; } x; x.f = f;
  unsigned int r = x.i + 0x7FFFu + ((x.i >> 16) & 1u);
  return (unsigned short)(r >> 16);
}

// ---------------- fused front-end: deg histogram + x->bf16 convert + weight repack ------
// Three independent jobs, block-range partitioned into ONE launch (R5-proven).
__global__ __launch_bounds__(256) void front_kernel(
    const int* __restrict__ dst, int* __restrict__ deg,
    const float* __restrict__ x, unsigned short* __restrict__ hbf,
    const float* __restrict__ Wl, const float* __restrict__ Wr,
    unsigned short* __restrict__ wout) {
  const int b = blockIdx.x;
  const int tid = threadIdx.x;
  if (b < DEG_BLOCKS) {
    // 4-wide fire-and-forget degree histogram (R1-proven)
    int e = (b * 256 + tid) * 4;
    if (e + 3 < EE) {
      int4 d = *(const int4*)(dst + e);
      atomicAdd(&deg[d.x], 1);
      atomicAdd(&deg[d.y], 1);
      atomicAdd(&deg[d.z], 1);
      atomicAdd(&deg[d.w], 1);
    } else {
      for (int i = e; i < EE; i++) atomicAdd(&deg[dst[i]], 1);
    }
  } else if (b < DEG_BLOCKS + CONV_BLOCKS) {
    int i = (b - DEG_BLOCKS) * 256 + tid;  // < NN*128/4 exactly
    float4 v = ((const float4*)x)[i];
    ushort4 o;
    o.x = f2bf(v.x); o.y = f2bf(v.y); o.z = f2bf(v.z); o.w = f2bf(v.w);
    ((ushort4*)hbf)[i] = o;
  } else {
    // weight repack into MFMA B-fragment order:
    // B[k][n]: k<128 -> Wl[l][n][k]; k>=128 -> Wr[l][n][k-128]
    // layout [l][ks][t][lane][j]: n = t*16 + (lane&15), k = ks*32 + (lane>>4)*8 + j
    int t0 = (b - DEG_BLOCKS - CONV_BLOCKS) * 256 + tid;  // < LL*4096 exactly
    int lane = t0 & 63;
    int t = (t0 >> 6) & 7;
    int ks = (t0 >> 9) & 7;
    int l = t0 >> 12;
    int n = t * 16 + (lane & 15);
    int kbase = ks * 32 + (lane >> 4) * 8;
    const float* Wsrc = (ks < 4) ? (Wl + ((size_t)(l * 128 + n) * 128 + kbase))
                                 : (Wr + ((size_t)(l * 128 + n) * 128 + (kbase - 128)));
#pragma unroll
    for (int j = 0; j < 8; j++) wout[(size_t)t0 * 8 + j] = f2bf(Wsrc[j]);
  }
}

// ---------------- fused exclusive scan (one block, 1024 threads, two-pass chunks) -------
// Replaces scan1+scan2+scan3 (-2 launches). ROUND-7 ISOLATION TEST: this is the only
// unproven component this round; gemm reverted to the R5-proven version.
__global__ __launch_bounds__(1024) void scan_kernel(
    const int* __restrict__ deg, int* __restrict__ rowptr, int* __restrict__ cursor) {
  __shared__ int wsum[16];
  const int tid = threadIdx.x, lane = tid & 63, wid = tid >> 6;
  const int CH = (NN + 1023) / 1024;  // 49
  int i0 = tid * CH;
  int i1 = i0 + CH; if (i1 > NN) i1 = NN;
  int s = 0;
  for (int i = i0; i < i1; i++) s += deg[i];
  // wave inclusive scan of chunk sums
  int x = s;
#pragma unroll
  for (int off = 1; off < 64; off <<= 1) {
    int y = __shfl_up(x, off, 64);
    if (lane >= off) x += y;
  }
  if (lane == 63) wsum[wid] = x;
  __syncthreads();
  if (tid == 0) {
    int run = 0;
#pragma unroll
    for (int w = 0; w < 16; w++) { int v = wsum[w]; wsum[w] = run; run += v; }
  }
  __syncthreads();
  int base = wsum[wid] + (x - s);  // exclusive prefix of this thread's chunk
  int run = base;
  for (int i = i0; i < i1; i++) {
    rowptr[i] = run;
    cursor[i] = run;
    run += deg[i];
  }
  if (tid == 0) rowptr[NN] = EE;
}

// XCD-partitioned CSR fill (R1-proven best: <=42.6us). blockIdx&7 -> XCD range; all
// atomics/col stores for a line come from one XCD (local L2, single writeback).
// 4-wide ILP: int4 dst load, 4 overlapped atomicAdd round-trips; grid 1568 blocks.
__global__ __launch_bounds__(256) void fill_kernel(
    const int* __restrict__ src, const int* __restrict__ dst,
    int* __restrict__ cursor, int* __restrict__ col, int E) {
  const int range = blockIdx.x & 7;
  const int chunk = blockIdx.x >> 3;
  const int lo = range * (NN / 8);
  const int hi = lo + (NN / 8);
  const int per = (E + FILL_CHUNKS - 1) / FILL_CHUNKS;
  const int e0 = chunk * per;
  const int e1 = (e0 + per < E) ? (e0 + per) : E;
  for (int eb = e0 + threadIdx.x * 4; eb < e1; eb += 256 * 4) {
    if (eb + 3 < e1) {
      int4 d4 = *(const int4*)(dst + eb);
      int dd[4] = {d4.x, d4.y, d4.z, d4.w};
      bool m[4];
      int sv[4], pos[4];
#pragma unroll
      for (int j = 0; j < 4; j++) m[j] = (dd[j] >= lo) & (dd[j] < hi);
#pragma unroll
      for (int j = 0; j < 4; j++) if (m[j]) sv[j] = src[eb + j];
#pragma unroll
      for (int j = 0; j < 4; j++) if (m[j]) pos[j] = atomicAdd(&cursor[dd[j]], 1);
#pragma unroll
      for (int j = 0; j < 4; j++) if (m[j]) col[pos[j]] = sv[j];
    } else {
      for (int e = eb; e < e1; e++) {
        int d = dst[e];
        if (d >= lo && d < hi) {
          int pos = atomicAdd(&cursor[d], 1);
          col[pos] = src[e];
        }
      }
    }
  }
}

// ---------------- CSR pull mean-aggregation (R1-proven paired-lane version) ----------
// Lanes 0-31 even edges, 32-63 odd edges; uint2 (8 B) per lane; shfl_xor(32) combine.
__global__ __launch_bounds__(256) void agg_kernel(
    const unsigned short* __restrict__ hbf, const int* __restrict__ rowptr,
    const int* __restrict__ col, unsigned short* __restrict__ agg, int N) {
  int node = blockIdx.x * 4 + (threadIdx.x >> 6);
  if (node >= N) return;
  int lane = threadIdx.x & 63;
  const int half = lane >> 5;   // 0: even edge of pair, 1: odd edge
  const int l32 = lane & 31;    // feature quad: features l32*4 .. l32*4+3
  int s = rowptr[node], e = rowptr[node + 1];
  float a0 = 0.f, a1 = 0.f, a2 = 0.f, a3 = 0.f;
  int i = s;
  // 8-pair (16-edge) main unroll
  for (; i + 15 < e; i += 16) {
    int idx[8];
#pragma unroll
    for (int j = 0; j < 8; j++) idx[j] = col[i + 2 * j + half];
    uint2 r[8];
#pragma unroll
    for (int j = 0; j < 8; j++) r[j] = ((const uint2*)(hbf + (size_t)idx[j] * 128))[l32];
#pragma unroll
    for (int j = 0; j < 8; j++) {
      a0 += bf2f(r[j].x & 0xffffu); a1 += bf2f(r[j].x >> 16);
      a2 += bf2f(r[j].y & 0xffffu); a3 += bf2f(r[j].y >> 16);
    }
  }
  if (i + 7 < e) {  // 4 pairs
    int idx[4];
#pragma unroll
    for (int j = 0; j < 4; j++) idx[j] = col[i + 2 * j + half];
    uint2 r[4];
#pragma unroll
    for (int j = 0; j < 4; j++) r[j] = ((const uint2*)(hbf + (size_t)idx[j] * 128))[l32];
#pragma unroll
    for (int j = 0; j < 4; j++) {
      a0 += bf2f(r[j].x & 0xffffu); a1 += bf2f(r[j].x >> 16);
      a2 += bf2f(r[j].y & 0xffffu); a3 += bf2f(r[j].y >> 16);
    }
    i += 8;
  }
  if (i + 3 < e) {  // 2 pairs
    int idx[2];
#pragma unroll
    for (int j = 0; j < 2; j++) idx[j] = col[i + 2 * j + half];
    uint2 r[2];
#pragma unroll
    for (int j = 0; j < 2; j++) r[j] = ((const uint2*)(hbf + (size_t)idx[j] * 128))[l32];
#pragma unroll
    for (int j = 0; j < 2; j++) {
      a0 += bf2f(r[j].x & 0xffffu); a1 += bf2f(r[j].x >> 16);
      a2 += bf2f(r[j].y & 0xffffu); a3 += bf2f(r[j].y >> 16);
    }
    i += 4;
  }
  if (i + 1 < e) {  // 1 pair
    int idx = col[i + half];
    uint2 r = ((const uint2*)(hbf + (size_t)idx * 128))[l32];
    a0 += bf2f(r.x & 0xffffu); a1 += bf2f(r.x >> 16);
    a2 += bf2f(r.y & 0xffffu); a3 += bf2f(r.y >> 16);
    i += 2;
  }
  if (i < e && half == 0) {  // final odd edge: half 0 only
    int idx = col[i];
    uint2 r = ((const uint2*)(hbf + (size_t)idx * 128))[l32];
    a0 += bf2f(r.x & 0xffffu); a1 += bf2f(r.x >> 16);
    a2 += bf2f(r.y & 0xffffu); a3 += bf2f(r.y >> 16);
  }
  // combine the two halves (lane ^ 32 holds the same feature columns, other edges)
  a0 += __shfl_xor(a0, 32);
  a1 += __shfl_xor(a1, 32);
  a2 += __shfl_xor(a2, 32);
  a3 += __shfl_xor(a3, 32);
  int dg = e - s;
  float inv = 1.0f / (float)(dg > 1 ? dg : 1);
  if (half == 0) {
    uint2 o;
    o.x = ((unsigned int)f2bf(a1 * inv) << 16) | (unsigned int)f2bf(a0 * inv);
    o.y = ((unsigned int)f2bf(a3 * inv) << 16) | (unsigned int)f2bf(a2 * inv);
    ((uint2*)(agg + (size_t)node * 128))[l32] = o;
  }
}

// ---------------- plain-bf16 MFMA GEMM + bias + LDS-epilogue LayerNorm + ReLU ----------------
// R5-proven version, reverted verbatim (round-6's shfl-LN 128-row variant failed absmax).
template <bool LAST>
__global__ __launch_bounds__(256) void gemm_ln_mfma_kernel(
    const unsigned short* __restrict__ agg, const unsigned short* __restrict__ h,
    const unsigned short* __restrict__ Bf, const float* __restrict__ bias,
    const float* __restrict__ gamma, const float* __restrict__ beta,
    unsigned short* __restrict__ out_bf, float* __restrict__ f_out, int N) {
  __shared__ unsigned short Bl[8 * 8 * 512];  // 64 KB
  __shared__ float reds[64][16];
  __shared__ float redss[64][16];
  __shared__ float mu_s[64], rs_s[64];
  const int tid = threadIdx.x;
  {
    const uint4* srcB = (const uint4*)Bf;
    uint4* dstB = (uint4*)Bl;
#pragma unroll
    for (int i = 0; i < 16; i++) dstB[tid + i * 256] = srcB[tid + i * 256];
  }
  __syncthreads();
  const int wave = tid >> 6, lane = tid & 63;
  const int ln16 = lane & 15, quad = lane >> 4;
  const int m0 = blockIdx.x * 64 + wave * 16;
  int row_a = m0 + ln16;
  if (row_a > N - 1) row_a = N - 1;  // clamp: MFMA rows independent; stores guarded below
  const size_t aoff = (size_t)row_a * 128 + quad * 8;

  float4v acc[8];
#pragma unroll
  for (int t = 0; t < 8; t++) acc[t] = (float4v)0.f;

#pragma unroll
  for (int ks = 0; ks < 8; ks++) {
    const unsigned short* ap = (ks < 4) ? (agg + aoff + ks * 32) : (h + aoff + (ks - 4) * 32);
    short8 a = *(const short8*)ap;
#pragma unroll
    for (int t = 0; t < 8; t++) {
      short8 b = *(const short8*)&Bl[(ks * 8 + t) * 512 + lane * 8];
      acc[t] = __builtin_amdgcn_mfma_f32_16x16x32_bf16(a, b, acc[t], 0, 0, 0);
    }
  }

  float bias_v[8], g_v[8], b_v[8];
#pragma unroll
  for (int t = 0; t < 8; t++) {
    int c = t * 16 + ln16;
    bias_v[t] = bias[c]; g_v[t] = gamma[c]; b_v[t] = beta[c];
  }
  // LDS-based LN statistics (no cross-lane shuffles — shfl-16 epilogue was the old bug)
#pragma unroll
  for (int r = 0; r < 4; r++) {
    float s = 0.f, ss = 0.f;
#pragma unroll
    for (int t = 0; t < 8; t++) {
      float val = acc[t][r] + bias_v[t];
      s += val; ss += val * val;
    }
    int rowblk = wave * 16 + quad * 4 + r;
    reds[rowblk][ln16] = s;
    redss[rowblk][ln16] = ss;
  }
  __syncthreads();
  if (tid < 64) {
    float s = 0.f, ss = 0.f;
#pragma unroll
    for (int g = 0; g < 16; g++) { s += reds[tid][g]; ss += redss[tid][g]; }
    float mu = s * (1.0f / 128.0f);
    float var = ss * (1.0f / 128.0f) - mu * mu;
    if (var < 0.f) var = 0.f;
    mu_s[tid] = mu;
    rs_s[tid] = rsqrtf(var + 1e-5f);
  }
  __syncthreads();
#pragma unroll
  for (int r = 0; r < 4; r++) {
    int row = m0 + quad * 4 + r;
    int rowblk = wave * 16 + quad * 4 + r;
    if (row < N) {
      float mu = mu_s[rowblk], rs = rs_s[rowblk];
#pragma unroll
      for (int t = 0; t < 8; t++) {
        float val = acc[t][r] + bias_v[t];
        float y = (val - mu) * rs * g_v[t] + b_v[t];
        y = y > 0.f ? y : 0.f;
        int cidx = t * 16 + ln16;
        if (LAST) {
          f_out[(size_t)row * 128 + cidx] = y;
        } else {
          out_bf[(size_t)row * 128 + cidx] = f2bf(y);
        }
      }
    }
  }
}

extern "C" void kernel_launch(void* const* d_in, const int* in_sizes, int n_in,
                              void* d_out, int out_size, void* d_ws, size_t ws_size,
                              hipStream_t stream) {
  const float* x = (const float*)d_in[0];
  const int* edge = (const int*)d_in[1];
  const float* Wl = (const float*)d_in[2];
  const float* bl = (const float*)d_in[3];
  const float* Wr = (const float*)d_in[4];
  const float* gamma = (const float*)d_in[5];
  const float* beta = (const float*)d_in[6];
  float* out = (float*)d_out;

  const int* srcv = edge;       // edge_index[0]
  const int* dstv = edge + EE;  // edge_index[1]

  char* p = (char*)d_ws;
  auto alloc = [&](size_t bytes) {
    char* r = p;
    p += (bytes + 255) & ~(size_t)255;
    return r;
  };
  const size_t bplane = (size_t)NN * 128 * 2;  // 12.8 MB bf16 plane
  unsigned short* xB = (unsigned short*)alloc(bplane);
  unsigned short* h1B = (unsigned short*)alloc(bplane);
  unsigned short* h2B = (unsigned short*)alloc(bplane);
  unsigned short* agB = (unsigned short*)alloc(bplane);
  unsigned short* BfB = (unsigned short*)alloc((size_t)LL * 32768 * 2);
  int* deg = (int*)alloc((size_t)NN * 4);
  int* cursor = (int*)alloc((size_t)NN * 4);
  int* rowptr = (int*)alloc((size_t)(NN + 1) * 4);
  int* colarr = (int*)alloc((size_t)EE * 4);
  if ((size_t)(p - (char*)d_ws) > ws_size) return;

  hipMemsetAsync(deg, 0, (size_t)NN * 4, stream);
  front_kernel<<<DEG_BLOCKS + CONV_BLOCKS + REPACK_BLOCKS, 256, 0, stream>>>(
      dstv, deg, x, xB, Wl, Wr, BfB);
  scan_kernel<<<1, 1024, 0, stream>>>(deg, rowptr, cursor);
  fill_kernel<<<8 * FILL_CHUNKS, 256, 0, stream>>>(srcv, dstv, cursor, colarr, EE);

  const int gemm_grid = (NN + 63) / 64;
  const int agg_grid = (NN + 3) / 4;

  // ---- layer 0 ----
  agg_kernel<<<agg_grid, 256, 0, stream>>>(xB, rowptr, colarr, agB, NN);
  gemm_ln_mfma_kernel<false><<<gemm_grid, 256, 0, stream>>>(
      agB, xB, BfB, bl, gamma, beta, h1B, nullptr, NN);

  // ---- layer 1 ----
  agg_kernel<<<agg_grid, 256, 0, stream>>>(h1B, rowptr, colarr, agB, NN);
  gemm_ln_mfma_kernel<false><<<gemm_grid, 256, 0, stream>>>(
      agB, h1B, BfB + 32768, bl + 128, gamma + 128, beta + 128, h2B, nullptr, NN);

  // ---- layer 2 ----
  agg_kernel<<<agg_grid, 256, 0, stream>>>(h2B, rowptr, colarr, agB, NN);
  gemm_ln_mfma_kernel<true><<<gemm_grid, 256, 0, stream>>>(
      agB, h2B, BfB + 2 * 32768, bl + 256, gamma + 256, beta + 256, nullptr, out, NN);
}

// Round 8
// 312.920 us; speedup vs baseline: 1.2790x; 1.2790x over previous
//
#include <hip/hip_runtime.h>
#include <hip/hip_bf16.h>
#include <stdint.h>

#define NN 50000
#define EE 800000
#define DD 128
#define LL 3
// CSR fill (R1-proven config): 196 chunks, x8 XCD ranges -> 1568 blocks, 4-wide ILP.
#define FILL_CHUNKS 196

// front_kernel block partition
#define DEG_BLOCKS 782                      // ceil(EE/4/256)
#define CONV_BLOCKS 6250                    // NN*128/4/256 exact
#define REPACK_BLOCKS 48                    // LL*8*8*64/256 exact
#define I8_BLOCKS 6250                      // NN*32/256 exact (x -> int8 plane)

typedef __attribute__((ext_vector_type(8))) short short8;
typedef __attribute__((ext_vector_type(4))) float float4v;

__device__ __forceinline__ float bf2f(unsigned int u) {
  union { unsigned int i; float f; } x; x.i = u << 16; return x.f;
}
__device__ __forceinline__ unsigned short f2bf(float f) {
  union { float f; unsigned int i; } x; x.f = f;
  unsigned int r = x.i + 0x7FFFu + ((x.i >> 16) & 1u);
  return (unsigned short)(r >> 16);
}

// int8 plane layout: plane byte position p holds original feature f(p) = (p&7)*16 + (p>>3).
// Inverse: p(f) = (f&15)*8 + (f>>4). This makes BOTH the gemm-epilogue int8 store (thread
// ln16 owns cols {16t+ln16} -> bytes [ln16*8, ln16*8+8)) and agg's agB write coalesced.
// Compensated by permuting the k-order of the Wl repack (MFMA sums over k in any order
// as long as A and B fragments agree).

// ---------------- fused front-end: deg + x->bf16 + weight repack + x->int8 ------
__global__ __launch_bounds__(256) void front_kernel(
    const int* __restrict__ dst, int* __restrict__ deg,
    const float* __restrict__ x, unsigned short* __restrict__ hbf,
    const float* __restrict__ Wl, const float* __restrict__ Wr,
    unsigned short* __restrict__ wout, unsigned* __restrict__ xi8) {
  const int b = blockIdx.x;
  const int tid = threadIdx.x;
  if (b < DEG_BLOCKS) {
    // 4-wide fire-and-forget degree histogram (R1-proven)
    int e = (b * 256 + tid) * 4;
    if (e + 3 < EE) {
      int4 d = *(const int4*)(dst + e);
      atomicAdd(&deg[d.x], 1);
      atomicAdd(&deg[d.y], 1);
      atomicAdd(&deg[d.z], 1);
      atomicAdd(&deg[d.w], 1);
    } else {
      for (int i = e; i < EE; i++) atomicAdd(&deg[dst[i]], 1);
    }
  } else if (b < DEG_BLOCKS + CONV_BLOCKS) {
    int i = (b - DEG_BLOCKS) * 256 + tid;  // < NN*128/4 exactly
    float4 v = ((const float4*)x)[i];
    ushort4 o;
    o.x = f2bf(v.x); o.y = f2bf(v.y); o.z = f2bf(v.z); o.w = f2bf(v.w);
    ((ushort4*)hbf)[i] = o;
  } else if (b < DEG_BLOCKS + CONV_BLOCKS + REPACK_BLOCKS) {
    // weight repack into MFMA B-fragment order.
    // ks<4 (Wl, agg operand): k-plane-position p sources original k = (p&7)*16 + (p>>3)
    // to match the permuted int8/agB plane. ks>=4 (Wr, h operand): linear as before.
    int t0 = (b - DEG_BLOCKS - CONV_BLOCKS) * 256 + tid;  // < LL*4096 exactly
    int lane = t0 & 63;
    int t = (t0 >> 6) & 7;
    int ks = (t0 >> 9) & 7;
    int l = t0 >> 12;
    int n = t * 16 + (lane & 15);
    int kbase = ks * 32 + (lane >> 4) * 8;  // plane position base
    if (ks < 4) {
      const float* wrow = Wl + (size_t)(l * 128 + n) * 128;
#pragma unroll
      for (int j = 0; j < 8; j++) {
        int p = kbase + j;
        int k = ((p & 7) << 4) | (p >> 3);
        wout[(size_t)t0 * 8 + j] = f2bf(wrow[k]);
      }
    } else {
      const float* wsrc = Wr + (size_t)(l * 128 + n) * 128 + (kbase - 128);
#pragma unroll
      for (int j = 0; j < 8; j++) wout[(size_t)t0 * 8 + j] = f2bf(wsrc[j]);
    }
  } else {
    // x -> int8 plane (permuted layout), scale 16, round-to-nearest-even, clamp +-127
    int gid = (b - DEG_BLOCKS - CONV_BLOCKS - REPACK_BLOCKS) * 256 + tid;  // < NN*32
    int n = gid >> 5, g = gid & 31;
    const float* xr = x + (size_t)n * 128;
    unsigned d = 0;
#pragma unroll
    for (int j = 0; j < 4; j++) {
      int p = 4 * g + j;
      int f = ((p & 7) << 4) | (p >> 3);
      float v = xr[f];
      int q = (int)rintf(v * 16.f);
      q = q > 127 ? 127 : (q < -127 ? -127 : q);
      d |= (unsigned)(q & 255) << (8 * j);
    }
    xi8[(size_t)n * 32 + g] = d;
  }
}

// 3-phase parallel exclusive scan (R1-proven; round-7's single-block fusion was 110us).
__global__ __launch_bounds__(256) void scan1_kernel(
    const int* __restrict__ deg, int* __restrict__ incl, int* __restrict__ partial, int N) {
  __shared__ int wsums[4];
  const int tid = threadIdx.x, lane = tid & 63, wid = tid >> 6;
  int i = blockIdx.x * 256 + tid;
  int v = (i < N) ? deg[i] : 0;
  int x = v;
#pragma unroll
  for (int off = 1; off < 64; off <<= 1) {
    int y = __shfl_up(x, off, 64);
    if (lane >= off) x += y;
  }
  if (lane == 63) wsums[wid] = x;
  __syncthreads();
  if (tid == 0) {
    int a0 = wsums[0], a1 = wsums[1], a2 = wsums[2];
    wsums[0] = 0; wsums[1] = a0; wsums[2] = a0 + a1; wsums[3] = a0 + a1 + a2;
  }
  __syncthreads();
  int inc = wsums[wid] + x;
  if (i < N) incl[i] = inc;
  if (tid == 255) partial[blockIdx.x] = inc;
}

__global__ __launch_bounds__(256) void scan2_kernel(int* __restrict__ partial, int P) {
  __shared__ int wsums[4];
  const int tid = threadIdx.x, lane = tid & 63, wid = tid >> 6;
  int v = (tid < P) ? partial[tid] : 0;
  int x = v;
#pragma unroll
  for (int off = 1; off < 64; off <<= 1) {
    int y = __shfl_up(x, off, 64);
    if (lane >= off) x += y;
  }
  if (lane == 63) wsums[wid] = x;
  __syncthreads();
  if (tid == 0) {
    int a0 = wsums[0], a1 = wsums[1], a2 = wsums[2];
    wsums[0] = 0; wsums[1] = a0; wsums[2] = a0 + a1; wsums[3] = a0 + a1 + a2;
  }
  __syncthreads();
  int excl = wsums[wid] + x - v;
  if (tid < P) partial[tid] = excl;
}

__global__ __launch_bounds__(256) void scan3_kernel(
    const int* __restrict__ incl, const int* __restrict__ deg, const int* __restrict__ partial,
    int* __restrict__ rowptr, int* __restrict__ cursor, int N) {
  int i = blockIdx.x * 256 + threadIdx.x;
  if (i < N) {
    int rp = incl[i] - deg[i] + partial[blockIdx.x];
    rowptr[i] = rp;
    cursor[i] = rp;
  }
  if (i == 0) rowptr[N] = EE;
}

// XCD-partitioned CSR fill (R1-proven best: <=42.6us).
__global__ __launch_bounds__(256) void fill_kernel(
    const int* __restrict__ src, const int* __restrict__ dst,
    int* __restrict__ cursor, int* __restrict__ col, int E) {
  const int range = blockIdx.x & 7;
  const int chunk = blockIdx.x >> 3;
  const int lo = range * (NN / 8);
  const int hi = lo + (NN / 8);
  const int per = (E + FILL_CHUNKS - 1) / FILL_CHUNKS;
  const int e0 = chunk * per;
  const int e1 = (e0 + per < E) ? (e0 + per) : E;
  for (int eb = e0 + threadIdx.x * 4; eb < e1; eb += 256 * 4) {
    if (eb + 3 < e1) {
      int4 d4 = *(const int4*)(dst + eb);
      int dd[4] = {d4.x, d4.y, d4.z, d4.w};
      bool m[4];
      int sv[4], pos[4];
#pragma unroll
      for (int j = 0; j < 4; j++) m[j] = (dd[j] >= lo) & (dd[j] < hi);
#pragma unroll
      for (int j = 0; j < 4; j++) if (m[j]) sv[j] = src[eb + j];
#pragma unroll
      for (int j = 0; j < 4; j++) if (m[j]) pos[j] = atomicAdd(&cursor[dd[j]], 1);
#pragma unroll
      for (int j = 0; j < 4; j++) if (m[j]) col[pos[j]] = sv[j];
    } else {
      for (int e = eb; e < e1; e++) {
        int d = dst[e];
        if (d >= lo && d < hi) {
          int pos = atomicAdd(&cursor[d], 1);
          col[pos] = src[e];
        }
      }
    }
  }
}

// ---------------- CSR pull mean-aggregation: INT8 gather (half the cache lines) ----------
// R8 theory: agg is L2 line-request bound (256B bf16 row = 4 lines/edge). int8 row = 128B
// = 2 lines/edge. Structure identical to R1-proven paired-lane version; exact int accum,
// x (1/16 * 1/deg) at the end. Plane is feature-permuted (see top comment).
__global__ __launch_bounds__(256) void agg_kernel(
    const unsigned* __restrict__ gi8, const int* __restrict__ rowptr,
    const int* __restrict__ col, unsigned short* __restrict__ agg, int N) {
  int node = blockIdx.x * 4 + (threadIdx.x >> 6);
  if (node >= N) return;
  int lane = threadIdx.x & 63;
  const int half = lane >> 5;   // 0: even edge of pair, 1: odd edge
  const int l32 = lane & 31;    // dword (4 plane-bytes) within the 128B row
  int s = rowptr[node], e = rowptr[node + 1];
  int a0 = 0, a1 = 0, a2 = 0, a3 = 0;
  int i = s;
  // 8-pair (16-edge) main unroll
  for (; i + 15 < e; i += 16) {
    int idx[8];
#pragma unroll
    for (int j = 0; j < 8; j++) idx[j] = col[i + 2 * j + half];
    unsigned r[8];
#pragma unroll
    for (int j = 0; j < 8; j++) r[j] = gi8[(size_t)idx[j] * 32 + l32];
#pragma unroll
    for (int j = 0; j < 8; j++) {
      a0 += (int)(r[j] << 24) >> 24;
      a1 += (int)(r[j] << 16) >> 24;
      a2 += (int)(r[j] << 8) >> 24;
      a3 += (int)r[j] >> 24;
    }
  }
  if (i + 7 < e) {  // 4 pairs
    int idx[4];
#pragma unroll
    for (int j = 0; j < 4; j++) idx[j] = col[i + 2 * j + half];
    unsigned r[4];
#pragma unroll
    for (int j = 0; j < 4; j++) r[j] = gi8[(size_t)idx[j] * 32 + l32];
#pragma unroll
    for (int j = 0; j < 4; j++) {
      a0 += (int)(r[j] << 24) >> 24;
      a1 += (int)(r[j] << 16) >> 24;
      a2 += (int)(r[j] << 8) >> 24;
      a3 += (int)r[j] >> 24;
    }
    i += 8;
  }
  if (i + 3 < e) {  // 2 pairs
    int idx[2];
#pragma unroll
    for (int j = 0; j < 2; j++) idx[j] = col[i + 2 * j + half];
    unsigned r[2];
#pragma unroll
    for (int j = 0; j < 2; j++) r[j] = gi8[(size_t)idx[j] * 32 + l32];
#pragma unroll
    for (int j = 0; j < 2; j++) {
      a0 += (int)(r[j] << 24) >> 24;
      a1 += (int)(r[j] << 16) >> 24;
      a2 += (int)(r[j] << 8) >> 24;
      a3 += (int)r[j] >> 24;
    }
    i += 4;
  }
  if (i + 1 < e) {  // 1 pair
    unsigned r = gi8[(size_t)col[i + half] * 32 + l32];
    a0 += (int)(r << 24) >> 24;
    a1 += (int)(r << 16) >> 24;
    a2 += (int)(r << 8) >> 24;
    a3 += (int)r >> 24;
    i += 2;
  }
  if (i < e && half == 0) {  // final odd edge: half 0 only
    unsigned r = gi8[(size_t)col[i] * 32 + l32];
    a0 += (int)(r << 24) >> 24;
    a1 += (int)(r << 16) >> 24;
    a2 += (int)(r << 8) >> 24;
    a3 += (int)r >> 24;
  }
  a0 += __shfl_xor(a0, 32);
  a1 += __shfl_xor(a1, 32);
  a2 += __shfl_xor(a2, 32);
  a3 += __shfl_xor(a3, 32);
  int dg = e - s;
  float inv = (1.0f / (float)(dg > 1 ? dg : 1)) * 0.0625f;  // /deg /16
  if (half == 0) {
    uint2 o;
    o.x = ((unsigned)f2bf((float)a1 * inv) << 16) | (unsigned)f2bf((float)a0 * inv);
    o.y = ((unsigned)f2bf((float)a3 * inv) << 16) | (unsigned)f2bf((float)a2 * inv);
    ((uint2*)(agg + (size_t)node * 128))[l32] = o;
  }
}

// ---------------- bf16 MFMA GEMM + bias + LDS-LN + ReLU (+ int8 h store) ----------------
// R5-proven core + epilogue; only addition: non-LAST path also stores the next layer's
// int8 gather plane (8 bytes/thread/row, coalesced by the permuted layout).
template <bool LAST>
__global__ __launch_bounds__(256) void gemm_ln_mfma_kernel(
    const unsigned short* __restrict__ agg, const unsigned short* __restrict__ h,
    const unsigned short* __restrict__ Bf, const float* __restrict__ bias,
    const float* __restrict__ gamma, const float* __restrict__ beta,
    unsigned short* __restrict__ out_bf, unsigned char* __restrict__ i8out,
    float* __restrict__ f_out, int N) {
  __shared__ unsigned short Bl[8 * 8 * 512];  // 64 KB
  __shared__ float reds[64][16];
  __shared__ float redss[64][16];
  __shared__ float mu_s[64], rs_s[64];
  const int tid = threadIdx.x;
  {
    const uint4* srcB = (const uint4*)Bf;
    uint4* dstB = (uint4*)Bl;
#pragma unroll
    for (int i = 0; i < 16; i++) dstB[tid + i * 256] = srcB[tid + i * 256];
  }
  __syncthreads();
  const int wave = tid >> 6, lane = tid & 63;
  const int ln16 = lane & 15, quad = lane >> 4;
  const int m0 = blockIdx.x * 64 + wave * 16;
  int row_a = m0 + ln16;
  if (row_a > N - 1) row_a = N - 1;  // clamp: MFMA rows independent; stores guarded below
  const size_t aoff = (size_t)row_a * 128 + quad * 8;

  float4v acc[8];
#pragma unroll
  for (int t = 0; t < 8; t++) acc[t] = (float4v)0.f;

#pragma unroll
  for (int ks = 0; ks < 8; ks++) {
    const unsigned short* ap = (ks < 4) ? (agg + aoff + ks * 32) : (h + aoff + (ks - 4) * 32);
    short8 a = *(const short8*)ap;
#pragma unroll
    for (int t = 0; t < 8; t++) {
      short8 b = *(const short8*)&Bl[(ks * 8 + t) * 512 + lane * 8];
      acc[t] = __builtin_amdgcn_mfma_f32_16x16x32_bf16(a, b, acc[t], 0, 0, 0);
    }
  }

  float bias_v[8], g_v[8], b_v[8];
#pragma unroll
  for (int t = 0; t < 8; t++) {
    int c = t * 16 + ln16;
    bias_v[t] = bias[c]; g_v[t] = gamma[c]; b_v[t] = beta[c];
  }
#pragma unroll
  for (int r = 0; r < 4; r++) {
    float s = 0.f, ss = 0.f;
#pragma unroll
    for (int t = 0; t < 8; t++) {
      float val = acc[t][r] + bias_v[t];
      s += val; ss += val * val;
    }
    int rowblk = wave * 16 + quad * 4 + r;
    reds[rowblk][ln16] = s;
    redss[rowblk][ln16] = ss;
  }
  __syncthreads();
  if (tid < 64) {
    float s = 0.f, ss = 0.f;
#pragma unroll
    for (int g = 0; g < 16; g++) { s += reds[tid][g]; ss += redss[tid][g]; }
    float mu = s * (1.0f / 128.0f);
    float var = ss * (1.0f / 128.0f) - mu * mu;
    if (var < 0.f) var = 0.f;
    mu_s[tid] = mu;
    rs_s[tid] = rsqrtf(var + 1e-5f);
  }
  __syncthreads();
#pragma unroll
  for (int r = 0; r < 4; r++) {
    int row = m0 + quad * 4 + r;
    int rowblk = wave * 16 + quad * 4 + r;
    if (row < N) {
      float mu = mu_s[rowblk], rs = rs_s[rowblk];
      unsigned lo = 0, hi = 0;
#pragma unroll
      for (int t = 0; t < 8; t++) {
        float val = acc[t][r] + bias_v[t];
        float y = (val - mu) * rs * g_v[t] + b_v[t];
        y = y > 0.f ? y : 0.f;
        int cidx = t * 16 + ln16;
        if (LAST) {
          f_out[(size_t)row * 128 + cidx] = y;
        } else {
          out_bf[(size_t)row * 128 + cidx] = f2bf(y);
          int q = (int)rintf(y * 16.f);
          q = q > 127 ? 127 : q;  // y >= 0 post-ReLU
          if (t < 4) lo |= (unsigned)(q & 255) << (8 * t);
          else       hi |= (unsigned)(q & 255) << (8 * (t - 4));
        }
      }
      if (!LAST) {
        uint2 o; o.x = lo; o.y = hi;
        *((uint2*)(i8out + (size_t)row * 128 + ln16 * 8)) = o;
      }
    }
  }
}

extern "C" void kernel_launch(void* const* d_in, const int* in_sizes, int n_in,
                              void* d_out, int out_size, void* d_ws, size_t ws_size,
                              hipStream_t stream) {
  const float* x = (const float*)d_in[0];
  const int* edge = (const int*)d_in[1];
  const float* Wl = (const float*)d_in[2];
  const float* bl = (const float*)d_in[3];
  const float* Wr = (const float*)d_in[4];
  const float* gamma = (const float*)d_in[5];
  const float* beta = (const float*)d_in[6];
  float* out = (float*)d_out;

  const int* srcv = edge;       // edge_index[0]
  const int* dstv = edge + EE;  // edge_index[1]

  char* p = (char*)d_ws;
  auto alloc = [&](size_t bytes) {
    char* r = p;
    p += (bytes + 255) & ~(size_t)255;
    return r;
  };
  const size_t bplane = (size_t)NN * 128 * 2;  // 12.8 MB bf16 plane
  unsigned short* xB = (unsigned short*)alloc(bplane);
  unsigned short* h1B = (unsigned short*)alloc(bplane);
  unsigned short* h2B = (unsigned short*)alloc(bplane);
  unsigned short* agB = (unsigned short*)alloc(bplane);
  unsigned short* BfB = (unsigned short*)alloc((size_t)LL * 32768 * 2);
  unsigned* i8a = (unsigned*)alloc((size_t)NN * 128);  // x-int8, reused for h2-int8
  unsigned* i8b = (unsigned*)alloc((size_t)NN * 128);  // h1-int8
  int* deg = (int*)alloc((size_t)NN * 4);
  int* incl = (int*)alloc((size_t)NN * 4);
  int* cursor = (int*)alloc((size_t)NN * 4);
  int* rowptr = (int*)alloc((size_t)(NN + 1) * 4);
  int* colarr = (int*)alloc((size_t)EE * 4);
  int* partial = (int*)alloc((size_t)256 * 4);
  if ((size_t)(p - (char*)d_ws) > ws_size) return;

  const int SCAN_BLOCKS = (NN + 255) / 256;  // 196

  hipMemsetAsync(deg, 0, (size_t)NN * 4, stream);
  front_kernel<<<DEG_BLOCKS + CONV_BLOCKS + REPACK_BLOCKS + I8_BLOCKS, 256, 0, stream>>>(
      dstv, deg, x, xB, Wl, Wr, BfB, i8a);
  scan1_kernel<<<SCAN_BLOCKS, 256, 0, stream>>>(deg, incl, partial, NN);
  scan2_kernel<<<1, 256, 0, stream>>>(partial, SCAN_BLOCKS);
  scan3_kernel<<<SCAN_BLOCKS, 256, 0, stream>>>(incl, deg, partial, rowptr, cursor, NN);
  fill_kernel<<<8 * FILL_CHUNKS, 256, 0, stream>>>(srcv, dstv, cursor, colarr, EE);

  const int gemm_grid = (NN + 63) / 64;
  const int agg_grid = (NN + 3) / 4;

  // ---- layer 0 ----
  agg_kernel<<<agg_grid, 256, 0, stream>>>(i8a, rowptr, colarr, agB, NN);
  gemm_ln_mfma_kernel<false><<<gemm_grid, 256, 0, stream>>>(
      agB, xB, BfB, bl, gamma, beta, h1B, (unsigned char*)i8b, nullptr, NN);

  // ---- layer 1 ----
  agg_kernel<<<agg_grid, 256, 0, stream>>>(i8b, rowptr, colarr, agB, NN);
  gemm_ln_mfma_kernel<false><<<gemm_grid, 256, 0, stream>>>(
      agB, h1B, BfB + 32768, bl + 128, gamma + 128, beta + 128, h2B, (unsigned char*)i8a,
      nullptr, NN);

  // ---- layer 2 ----
  agg_kernel<<<agg_grid, 256, 0, stream>>>(i8a, rowptr, colarr, agB, NN);
  gemm_ln_mfma_kernel<true><<<gemm_grid, 256, 0, stream>>>(
      agB, h2B, BfB + 2 * 32768, bl + 256, gamma + 256, beta + 256, nullptr, nullptr, out, NN);
}

// Round 9
// 312.342 us; speedup vs baseline: 1.2814x; 1.0019x over previous
//
#include <hip/hip_runtime.h>
#include <hip/hip_bf16.h>
#include <stdint.h>

#define NN 50000
#define EE 800000
#define DD 128
#define LL 3
// CSR fill (R1-proven config): 196 chunks, x8 XCD ranges -> 1568 blocks, 4-wide ILP.
#define FILL_CHUNKS 196

// front_kernel block partition
#define DEG_BLOCKS 782                      // ceil(EE/4/256)
#define CONV_BLOCKS 6250                    // NN*128/4/256 exact (convert + fused i8)
#define REPACK_BLOCKS 48                    // LL*8*8*64/256 exact

typedef __attribute__((ext_vector_type(8))) short short8;
typedef __attribute__((ext_vector_type(4))) float float4v;

__device__ __forceinline__ float bf2f(unsigned int u) {
  union { unsigned int i; float f; } x; x.i = u << 16; return x.f;
}
__device__ __forceinline__ unsigned short f2bf(float f) {
  union { float f; unsigned int i; } x; x.f = f;
  unsigned int r = x.i + 0x7FFFu + ((x.i >> 16) & 1u);
  return (unsigned short)(r >> 16);
}

// int8 plane layout: plane byte position p holds original feature f(p) = (p&7)*16 + (p>>3).
// Inverse: p(f) = (f&15)*8 + (f>>4). Makes the gemm-epilogue i8 store AND agg's reads
// coalesced; compensated by permuting the k-order of the Wl repack (R8-proven).

// ---------------- fused front-end: deg + x->{bf16,int8} + weight repack ------
// R9: i8 quantization fused into the convert branch via LDS byte-scatter stage —
// removes R8's scattered stride-16 re-read of x (the +20us front regression).
__global__ __launch_bounds__(256) void front_kernel(
    const int* __restrict__ dst, int* __restrict__ deg,
    const float* __restrict__ x, unsigned short* __restrict__ hbf,
    const float* __restrict__ Wl, const float* __restrict__ Wr,
    unsigned short* __restrict__ wout, unsigned* __restrict__ xi8) {
  __shared__ unsigned char l8[1024];  // 8 rows x 128 B permuted i8 stage
  const int b = blockIdx.x;
  const int tid = threadIdx.x;
  if (b < DEG_BLOCKS) {
    // 4-wide fire-and-forget degree histogram (R1-proven)
    int e = (b * 256 + tid) * 4;
    if (e + 3 < EE) {
      int4 d = *(const int4*)(dst + e);
      atomicAdd(&deg[d.x], 1);
      atomicAdd(&deg[d.y], 1);
      atomicAdd(&deg[d.z], 1);
      atomicAdd(&deg[d.w], 1);
    } else {
      for (int i = e; i < EE; i++) atomicAdd(&deg[dst[i]], 1);
    }
  } else if (b < DEG_BLOCKS + CONV_BLOCKS) {
    const int bi = b - DEG_BLOCKS;       // 0..6249; block owns 8 node rows
    const int i = bi * 256 + tid;        // float4 index (exact, no guard)
    float4 v = ((const float4*)x)[i];
    ushort4 o;
    o.x = f2bf(v.x); o.y = f2bf(v.y); o.z = f2bf(v.z); o.w = f2bf(v.w);
    ((ushort4*)hbf)[i] = o;
    // fused i8: quantize the 4 features already in registers, byte-scatter to LDS
    const int rr = tid >> 5;             // row within the 8-row group
    const int ff = (tid & 31) * 4;       // feature base within the row
    float vv[4] = {v.x, v.y, v.z, v.w};
#pragma unroll
    for (int j = 0; j < 4; j++) {
      int f = ff + j;
      int q = (int)rintf(vv[j] * 16.f);
      q = q > 127 ? 127 : (q < -127 ? -127 : q);
      int p = ((f & 15) << 3) | (f >> 4);
      l8[rr * 128 + p] = (unsigned char)(q & 255);
    }
    __syncthreads();
    xi8[(size_t)bi * 256 + tid] = ((const unsigned*)l8)[tid];  // coalesced 1KB/block
  } else {
    // weight repack into MFMA B-fragment order.
    // ks<4 (Wl, agg operand): k-plane-position p sources original k = (p&7)*16 + (p>>3)
    // to match the permuted int8/agB plane. ks>=4 (Wr, h operand): linear.
    int t0 = (b - DEG_BLOCKS - CONV_BLOCKS) * 256 + tid;  // < LL*4096 exactly
    int lane = t0 & 63;
    int t = (t0 >> 6) & 7;
    int ks = (t0 >> 9) & 7;
    int l = t0 >> 12;
    int n = t * 16 + (lane & 15);
    int kbase = ks * 32 + (lane >> 4) * 8;  // plane position base
    if (ks < 4) {
      const float* wrow = Wl + (size_t)(l * 128 + n) * 128;
#pragma unroll
      for (int j = 0; j < 8; j++) {
        int p = kbase + j;
        int k = ((p & 7) << 4) | (p >> 3);
        wout[(size_t)t0 * 8 + j] = f2bf(wrow[k]);
      }
    } else {
      const float* wsrc = Wr + (size_t)(l * 128 + n) * 128 + (kbase - 128);
#pragma unroll
      for (int j = 0; j < 8; j++) wout[(size_t)t0 * 8 + j] = f2bf(wsrc[j]);
    }
  }
}

// 3-phase parallel exclusive scan (R1-proven).
__global__ __launch_bounds__(256) void scan1_kernel(
    const int* __restrict__ deg, int* __restrict__ incl, int* __restrict__ partial, int N) {
  __shared__ int wsums[4];
  const int tid = threadIdx.x, lane = tid & 63, wid = tid >> 6;
  int i = blockIdx.x * 256 + tid;
  int v = (i < N) ? deg[i] : 0;
  int x = v;
#pragma unroll
  for (int off = 1; off < 64; off <<= 1) {
    int y = __shfl_up(x, off, 64);
    if (lane >= off) x += y;
  }
  if (lane == 63) wsums[wid] = x;
  __syncthreads();
  if (tid == 0) {
    int a0 = wsums[0], a1 = wsums[1], a2 = wsums[2];
    wsums[0] = 0; wsums[1] = a0; wsums[2] = a0 + a1; wsums[3] = a0 + a1 + a2;
  }
  __syncthreads();
  int inc = wsums[wid] + x;
  if (i < N) incl[i] = inc;
  if (tid == 255) partial[blockIdx.x] = inc;
}

__global__ __launch_bounds__(256) void scan2_kernel(int* __restrict__ partial, int P) {
  __shared__ int wsums[4];
  const int tid = threadIdx.x, lane = tid & 63, wid = tid >> 6;
  int v = (tid < P) ? partial[tid] : 0;
  int x = v;
#pragma unroll
  for (int off = 1; off < 64; off <<= 1) {
    int y = __shfl_up(x, off, 64);
    if (lane >= off) x += y;
  }
  if (lane == 63) wsums[wid] = x;
  __syncthreads();
  if (tid == 0) {
    int a0 = wsums[0], a1 = wsums[1], a2 = wsums[2];
    wsums[0] = 0; wsums[1] = a0; wsums[2] = a0 + a1; wsums[3] = a0 + a1 + a2;
  }
  __syncthreads();
  int excl = wsums[wid] + x - v;
  if (tid < P) partial[tid] = excl;
}

__global__ __launch_bounds__(256) void scan3_kernel(
    const int* __restrict__ incl, const int* __restrict__ deg, const int* __restrict__ partial,
    int* __restrict__ rowptr, int* __restrict__ cursor, int N) {
  int i = blockIdx.x * 256 + threadIdx.x;
  if (i < N) {
    int rp = incl[i] - deg[i] + partial[blockIdx.x];
    rowptr[i] = rp;
    cursor[i] = rp;
  }
  if (i == 0) rowptr[N] = EE;
}

// XCD-partitioned CSR fill (R1-proven best: <=42.6us).
__global__ __launch_bounds__(256) void fill_kernel(
    const int* __restrict__ src, const int* __restrict__ dst,
    int* __restrict__ cursor, int* __restrict__ col, int E) {
  const int range = blockIdx.x & 7;
  const int chunk = blockIdx.x >> 3;
  const int lo = range * (NN / 8);
  const int hi = lo + (NN / 8);
  const int per = (E + FILL_CHUNKS - 1) / FILL_CHUNKS;
  const int e0 = chunk * per;
  const int e1 = (e0 + per < E) ? (e0 + per) : E;
  for (int eb = e0 + threadIdx.x * 4; eb < e1; eb += 256 * 4) {
    if (eb + 3 < e1) {
      int4 d4 = *(const int4*)(dst + eb);
      int dd[4] = {d4.x, d4.y, d4.z, d4.w};
      bool m[4];
      int sv[4], pos[4];
#pragma unroll
      for (int j = 0; j < 4; j++) m[j] = (dd[j] >= lo) & (dd[j] < hi);
#pragma unroll
      for (int j = 0; j < 4; j++) if (m[j]) sv[j] = src[eb + j];
#pragma unroll
      for (int j = 0; j < 4; j++) if (m[j]) pos[j] = atomicAdd(&cursor[dd[j]], 1);
#pragma unroll
      for (int j = 0; j < 4; j++) if (m[j]) col[pos[j]] = sv[j];
    } else {
      for (int e = eb; e < e1; e++) {
        int d = dst[e];
        if (d >= lo && d < hi) {
          int pos = atomicAdd(&cursor[d], 1);
          col[pos] = src[e];
        }
      }
    }
  }
}

// ---------------- CSR pull mean-aggregation: INT8 gather (R8-proven) ----------
__global__ __launch_bounds__(256) void agg_kernel(
    const unsigned* __restrict__ gi8, const int* __restrict__ rowptr,
    const int* __restrict__ col, unsigned short* __restrict__ agg, int N) {
  int node = blockIdx.x * 4 + (threadIdx.x >> 6);
  if (node >= N) return;
  int lane = threadIdx.x & 63;
  const int half = lane >> 5;   // 0: even edge of pair, 1: odd edge
  const int l32 = lane & 31;    // dword (4 plane-bytes) within the 128B row
  int s = rowptr[node], e = rowptr[node + 1];
  int a0 = 0, a1 = 0, a2 = 0, a3 = 0;
  int i = s;
  // 8-pair (16-edge) main unroll
  for (; i + 15 < e; i += 16) {
    int idx[8];
#pragma unroll
    for (int j = 0; j < 8; j++) idx[j] = col[i + 2 * j + half];
    unsigned r[8];
#pragma unroll
    for (int j = 0; j < 8; j++) r[j] = gi8[(size_t)idx[j] * 32 + l32];
#pragma unroll
    for (int j = 0; j < 8; j++) {
      a0 += (int)(r[j] << 24) >> 24;
      a1 += (int)(r[j] << 16) >> 24;
      a2 += (int)(r[j] << 8) >> 24;
      a3 += (int)r[j] >> 24;
    }
  }
  if (i + 7 < e) {  // 4 pairs
    int idx[4];
#pragma unroll
    for (int j = 0; j < 4; j++) idx[j] = col[i + 2 * j + half];
    unsigned r[4];
#pragma unroll
    for (int j = 0; j < 4; j++) r[j] = gi8[(size_t)idx[j] * 32 + l32];
#pragma unroll
    for (int j = 0; j < 4; j++) {
      a0 += (int)(r[j] << 24) >> 24;
      a1 += (int)(r[j] << 16) >> 24;
      a2 += (int)(r[j] << 8) >> 24;
      a3 += (int)r[j] >> 24;
    }
    i += 8;
  }
  if (i + 3 < e) {  // 2 pairs
    int idx[2];
#pragma unroll
    for (int j = 0; j < 2; j++) idx[j] = col[i + 2 * j + half];
    unsigned r[2];
#pragma unroll
    for (int j = 0; j < 2; j++) r[j] = gi8[(size_t)idx[j] * 32 + l32];
#pragma unroll
    for (int j = 0; j < 2; j++) {
      a0 += (int)(r[j] << 24) >> 24;
      a1 += (int)(r[j] << 16) >> 24;
      a2 += (int)(r[j] << 8) >> 24;
      a3 += (int)r[j] >> 24;
    }
    i += 4;
  }
  if (i + 1 < e) {  // 1 pair
    unsigned r = gi8[(size_t)col[i + half] * 32 + l32];
    a0 += (int)(r << 24) >> 24;
    a1 += (int)(r << 16) >> 24;
    a2 += (int)(r << 8) >> 24;
    a3 += (int)r >> 24;
    i += 2;
  }
  if (i < e && half == 0) {  // final odd edge: half 0 only
    unsigned r = gi8[(size_t)col[i] * 32 + l32];
    a0 += (int)(r << 24) >> 24;
    a1 += (int)(r << 16) >> 24;
    a2 += (int)(r << 8) >> 24;
    a3 += (int)r >> 24;
  }
  a0 += __shfl_xor(a0, 32);
  a1 += __shfl_xor(a1, 32);
  a2 += __shfl_xor(a2, 32);
  a3 += __shfl_xor(a3, 32);
  int dg = e - s;
  float inv = (1.0f / (float)(dg > 1 ? dg : 1)) * 0.0625f;  // /deg /16
  if (half == 0) {
    uint2 o;
    o.x = ((unsigned)f2bf((float)a1 * inv) << 16) | (unsigned)f2bf((float)a0 * inv);
    o.y = ((unsigned)f2bf((float)a3 * inv) << 16) | (unsigned)f2bf((float)a2 * inv);
    ((uint2*)(agg + (size_t)node * 128))[l32] = o;
  }
}

// ---------------- bf16 MFMA GEMM + bias + LDS-LN + ReLU (+ int8 h store) ----------------
// R5-proven core + epilogue; R8-proven int8 h store.
template <bool LAST>
__global__ __launch_bounds__(256) void gemm_ln_mfma_kernel(
    const unsigned short* __restrict__ agg, const unsigned short* __restrict__ h,
    const unsigned short* __restrict__ Bf, const float* __restrict__ bias,
    const float* __restrict__ gamma, const float* __restrict__ beta,
    unsigned short* __restrict__ out_bf, unsigned char* __restrict__ i8out,
    float* __restrict__ f_out, int N) {
  __shared__ unsigned short Bl[8 * 8 * 512];  // 64 KB
  __shared__ float reds[64][16];
  __shared__ float redss[64][16];
  __shared__ float mu_s[64], rs_s[64];
  const int tid = threadIdx.x;
  {
    const uint4* srcB = (const uint4*)Bf;
    uint4* dstB = (uint4*)Bl;
#pragma unroll
    for (int i = 0; i < 16; i++) dstB[tid + i * 256] = srcB[tid + i * 256];
  }
  __syncthreads();
  const int wave = tid >> 6, lane = tid & 63;
  const int ln16 = lane & 15, quad = lane >> 4;
  const int m0 = blockIdx.x * 64 + wave * 16;
  int row_a = m0 + ln16;
  if (row_a > N - 1) row_a = N - 1;  // clamp: MFMA rows independent; stores guarded below
  const size_t aoff = (size_t)row_a * 128 + quad * 8;

  float4v acc[8];
#pragma unroll
  for (int t = 0; t < 8; t++) acc[t] = (float4v)0.f;

#pragma unroll
  for (int ks = 0; ks < 8; ks++) {
    const unsigned short* ap = (ks < 4) ? (agg + aoff + ks * 32) : (h + aoff + (ks - 4) * 32);
    short8 a = *(const short8*)ap;
#pragma unroll
    for (int t = 0; t < 8; t++) {
      short8 b = *(const short8*)&Bl[(ks * 8 + t) * 512 + lane * 8];
      acc[t] = __builtin_amdgcn_mfma_f32_16x16x32_bf16(a, b, acc[t], 0, 0, 0);
    }
  }

  float bias_v[8], g_v[8], b_v[8];
#pragma unroll
  for (int t = 0; t < 8; t++) {
    int c = t * 16 + ln16;
    bias_v[t] = bias[c]; g_v[t] = gamma[c]; b_v[t] = beta[c];
  }
#pragma unroll
  for (int r = 0; r < 4; r++) {
    float s = 0.f, ss = 0.f;
#pragma unroll
    for (int t = 0; t < 8; t++) {
      float val = acc[t][r] + bias_v[t];
      s += val; ss += val * val;
    }
    int rowblk = wave * 16 + quad * 4 + r;
    reds[rowblk][ln16] = s;
    redss[rowblk][ln16] = ss;
  }
  __syncthreads();
  if (tid < 64) {
    float s = 0.f, ss = 0.f;
#pragma unroll
    for (int g = 0; g < 16; g++) { s += reds[tid][g]; ss += redss[tid][g]; }
    float mu = s * (1.0f / 128.0f);
    float var = ss * (1.0f / 128.0f) - mu * mu;
    if (var < 0.f) var = 0.f;
    mu_s[tid] = mu;
    rs_s[tid] = rsqrtf(var + 1e-5f);
  }
  __syncthreads();
#pragma unroll
  for (int r = 0; r < 4; r++) {
    int row = m0 + quad * 4 + r;
    int rowblk = wave * 16 + quad * 4 + r;
    if (row < N) {
      float mu = mu_s[rowblk], rs = rs_s[rowblk];
      unsigned lo = 0, hi = 0;
#pragma unroll
      for (int t = 0; t < 8; t++) {
        float val = acc[t][r] + bias_v[t];
        float y = (val - mu) * rs * g_v[t] + b_v[t];
        y = y > 0.f ? y : 0.f;
        int cidx = t * 16 + ln16;
        if (LAST) {
          f_out[(size_t)row * 128 + cidx] = y;
        } else {
          out_bf[(size_t)row * 128 + cidx] = f2bf(y);
          int q = (int)rintf(y * 16.f);
          q = q > 127 ? 127 : q;  // y >= 0 post-ReLU
          if (t < 4) lo |= (unsigned)(q & 255) << (8 * t);
          else       hi |= (unsigned)(q & 255) << (8 * (t - 4));
        }
      }
      if (!LAST) {
        uint2 o; o.x = lo; o.y = hi;
        *((uint2*)(i8out + (size_t)row * 128 + ln16 * 8)) = o;
      }
    }
  }
}

extern "C" void kernel_launch(void* const* d_in, const int* in_sizes, int n_in,
                              void* d_out, int out_size, void* d_ws, size_t ws_size,
                              hipStream_t stream) {
  const float* x = (const float*)d_in[0];
  const int* edge = (const int*)d_in[1];
  const float* Wl = (const float*)d_in[2];
  const float* bl = (const float*)d_in[3];
  const float* Wr = (const float*)d_in[4];
  const float* gamma = (const float*)d_in[5];
  const float* beta = (const float*)d_in[6];
  float* out = (float*)d_out;

  const int* srcv = edge;       // edge_index[0]
  const int* dstv = edge + EE;  // edge_index[1]

  char* p = (char*)d_ws;
  auto alloc = [&](size_t bytes) {
    char* r = p;
    p += (bytes + 255) & ~(size_t)255;
    return r;
  };
  const size_t bplane = (size_t)NN * 128 * 2;  // 12.8 MB bf16 plane
  unsigned short* xB = (unsigned short*)alloc(bplane);
  unsigned short* h1B = (unsigned short*)alloc(bplane);
  unsigned short* h2B = (unsigned short*)alloc(bplane);
  unsigned short* agB = (unsigned short*)alloc(bplane);
  unsigned short* BfB = (unsigned short*)alloc((size_t)LL * 32768 * 2);
  unsigned* i8a = (unsigned*)alloc((size_t)NN * 128);  // x-int8, reused for h2-int8
  unsigned* i8b = (unsigned*)alloc((size_t)NN * 128);  // h1-int8
  int* deg = (int*)alloc((size_t)NN * 4);
  int* incl = (int*)alloc((size_t)NN * 4);
  int* cursor = (int*)alloc((size_t)NN * 4);
  int* rowptr = (int*)alloc((size_t)(NN + 1) * 4);
  int* colarr = (int*)alloc((size_t)EE * 4);
  int* partial = (int*)alloc((size_t)256 * 4);
  if ((size_t)(p - (char*)d_ws) > ws_size) return;

  const int SCAN_BLOCKS = (NN + 255) / 256;  // 196

  hipMemsetAsync(deg, 0, (size_t)NN * 4, stream);
  front_kernel<<<DEG_BLOCKS + CONV_BLOCKS + REPACK_BLOCKS, 256, 0, stream>>>(
      dstv, deg, x, xB, Wl, Wr, BfB, i8a);
  scan1_kernel<<<SCAN_BLOCKS, 256, 0, stream>>>(deg, incl, partial, NN);
  scan2_kernel<<<1, 256, 0, stream>>>(partial, SCAN_BLOCKS);
  scan3_kernel<<<SCAN_BLOCKS, 256, 0, stream>>>(incl, deg, partial, rowptr, cursor, NN);
  fill_kernel<<<8 * FILL_CHUNKS, 256, 0, stream>>>(srcv, dstv, cursor, colarr, EE);

  const int gemm_grid = (NN + 63) / 64;
  const int agg_grid = (NN + 3) / 4;

  // ---- layer 0 ----
  agg_kernel<<<agg_grid, 256, 0, stream>>>(i8a, rowptr, colarr, agB, NN);
  gemm_ln_mfma_kernel<false><<<gemm_grid, 256, 0, stream>>>(
      agB, xB, BfB, bl, gamma, beta, h1B, (unsigned char*)i8b, nullptr, NN);

  // ---- layer 1 ----
  agg_kernel<<<agg_grid, 256, 0, stream>>>(i8b, rowptr, colarr, agB, NN);
  gemm_ln_mfma_kernel<false><<<gemm_grid, 256, 0, stream>>>(
      agB, h1B, BfB + 32768, bl + 128, gamma + 128, beta + 128, h2B, (unsigned char*)i8a,
      nullptr, NN);

  // ---- layer 2 ----
  agg_kernel<<<agg_grid, 256, 0, stream>>>(i8a, rowptr, colarr, agB, NN);
  gemm_ln_mfma_kernel<true><<<gemm_grid, 256, 0, stream>>>(
      agB, h2B, BfB + 2 * 32768, bl + 256, gamma + 256, beta + 256, nullptr, nullptr, out, NN);
}